// Round 2
// baseline (499.035 us; speedup 1.0000x reference)
//
#include <hip/hip_runtime.h>
#include <hip/hip_bf16.h>
#include <cstdint>
#include <cstddef>

// ---------------------------------------------------------------------------
// MultiHeadAttention fused pipeline, bf16 MFMA compute.
//   B=4, S=2048, D=1024, H=16, dk=64  (derived from in_sizes where possible)
// Stages:
//   1. cvt fp32->bf16 for x_q/x_k/x_v and W_q/W_k/W_v/W_o
//   2. rope cos/sin tables  [S][32] fp32
//   3. GEMM (bf16 out): qp/kp/vp = X @ W^T + b   (token-major [B*S, D])
//   4. reshape: Q,K -> RoPE -> [B,H,S,dk]; V -> [B,H,dk,S] (transposed)
//   5. flash attention (causal, online softmax) -> ctx bf16 [B*S, D]
//   6. GEMM (f32 out): out = ctx @ W_o^T + b_o
// Workspace aliasing: Qh/Kh/Vtr reuse xq/xk/xv (dead after QKV GEMMs);
// ctx reuses qp (dead after reshape). Peak ws ~110 MB.
// ---------------------------------------------------------------------------

typedef __attribute__((ext_vector_type(8))) short short8;   // 8 x bf16 (4 VGPR)
typedef __attribute__((ext_vector_type(4))) float f32x4;    // MFMA C/D frag
typedef unsigned short u16;

#define LOG2E 1.44269504088896340736f

__device__ __forceinline__ u16 f2bf(float f) {
  __hip_bfloat16 h = __float2bfloat16(f);
  return *reinterpret_cast<u16*>(&h);
}
__device__ __forceinline__ float bf2f(short bits) {
  unsigned int u = ((unsigned int)(u16)bits) << 16;
  return __uint_as_float(u);
}
__device__ __forceinline__ void gload_lds16(const void* g, void* l) {
  __builtin_amdgcn_global_load_lds(
      (const __attribute__((address_space(1))) void*)g,
      (__attribute__((address_space(3))) void*)l, 16, 0, 0);
}

// ---------------------------------------------------------------------------
// 1. fp32 -> bf16 convert (vectorized float4 -> ushort4)
// ---------------------------------------------------------------------------
__global__ void cvt_f32_to_bf16(const float* __restrict__ in, u16* __restrict__ out, int n4) {
  const int stride = gridDim.x * blockDim.x;
  for (int i = blockIdx.x * blockDim.x + threadIdx.x; i < n4; i += stride) {
    const float4 v = ((const float4*)in)[i];
    ushort4 o;
    o.x = f2bf(v.x); o.y = f2bf(v.y); o.z = f2bf(v.z); o.w = f2bf(v.w);
    ((ushort4*)out)[i] = o;
  }
}

// ---------------------------------------------------------------------------
// 2. RoPE tables: cos/sin(s * 10000^(-i/32)), i in [0,32)
// ---------------------------------------------------------------------------
__global__ void rope_tables(float* __restrict__ cost, float* __restrict__ sint, int S) {
  const int idx = blockIdx.x * blockDim.x + threadIdx.x;
  if (idx >= S * 32) return;
  const int s = idx >> 5, i = idx & 31;
  const float invf = powf(10000.0f, -(float)i * (1.0f / 32.0f));
  const float ang = (float)s * invf;
  cost[idx] = cosf(ang);
  sint[idx] = sinf(ang);
}

// ---------------------------------------------------------------------------
// 3/6. GEMM  C[M,N] = A[M,K] @ Bt[N,K]^T + bias
//   128x128 tile, BK=64, 4 waves (2x2), 16x16x32 bf16 MFMA.
//   global_load_lds staging; LDS rows are 128B (8 x 16B chunks), XOR-swizzled
//   (chunk ^= row&7) via pre-swizzled GLOBAL source (m201 pattern: linear LDS
//   dest + inverse-swizzled source + swizzled ds_read -> ~2-way banks).
// ---------------------------------------------------------------------------
template<int OUT_F32>
__global__ __launch_bounds__(256, 2)
void gemm_bt(const u16* __restrict__ A, const u16* __restrict__ Bt,
             const float* __restrict__ bias, void* __restrict__ Cout,
             int M, int N, int K) {
  __shared__ u16 As[128 * 64];
  __shared__ u16 Bs[128 * 64];
  const int tid = threadIdx.x;
  const int wid = tid >> 6;
  const int lane = tid & 63;
  const int g = lane >> 4, c = lane & 15;
  const int m0 = blockIdx.x * 128;
  const int n0 = blockIdx.y * 128;
  const int wr = wid >> 1, wc = wid & 1;   // wave grid 2x2, each wave 64x64 out

  f32x4 acc[4][4];
#pragma unroll
  for (int i = 0; i < 4; ++i)
#pragma unroll
    for (int j = 0; j < 4; ++j) acc[i][j] = (f32x4)(0.0f);

  const int kIters = K >> 6;
  for (int kt = 0; kt < kIters; ++kt) {
    const int k0 = kt << 6;
    // stage both 128x64 bf16 tiles: 1024 chunks of 16B each, 4 issues x 256 thr
#pragma unroll
    for (int i = 0; i < 4; ++i) {
      const int chunk = i * 256 + tid;
      const int row = chunk >> 3;
      const int scz = (chunk & 7) ^ (row & 7);       // inverse-swizzled source
      gload_lds16(A + (size_t)(m0 + row) * K + (k0 + scz * 8),
                  (char*)As + (size_t)(i * 256 + (wid << 6)) * 16);
      gload_lds16(Bt + (size_t)(n0 + row) * K + (k0 + scz * 8),
                  (char*)Bs + (size_t)(i * 256 + (wid << 6)) * 16);
    }
    __syncthreads();
#pragma unroll
    for (int ks = 0; ks < 2; ++ks) {
      short8 af[4], bfr[4];
#pragma unroll
      for (int mi = 0; mi < 4; ++mi) {
        const int row = wr * 64 + mi * 16 + c;
        const int cch = (g + ks * 4) ^ (row & 7);    // swizzled read
        af[mi] = *(const short8*)((const char*)As + row * 128 + cch * 16);
      }
#pragma unroll
      for (int ni = 0; ni < 4; ++ni) {
        const int row = wc * 64 + ni * 16 + c;
        const int cch = (g + ks * 4) ^ (row & 7);
        bfr[ni] = *(const short8*)((const char*)Bs + row * 128 + cch * 16);
      }
#pragma unroll
      for (int mi = 0; mi < 4; ++mi)
#pragma unroll
        for (int ni = 0; ni < 4; ++ni)
          acc[mi][ni] = __builtin_amdgcn_mfma_f32_16x16x32_bf16(af[mi], bfr[ni], acc[mi][ni], 0, 0, 0);
    }
    __syncthreads();
  }

  float bv[4];
#pragma unroll
  for (int ni = 0; ni < 4; ++ni) bv[ni] = bias[n0 + wc * 64 + ni * 16 + c];

  // C/D layout: col = lane&15, row = (lane>>4)*4 + reg   [m89/m91 verified]
#pragma unroll
  for (int mi = 0; mi < 4; ++mi)
#pragma unroll
    for (int ni = 0; ni < 4; ++ni)
#pragma unroll
      for (int r = 0; r < 4; ++r) {
        const int row = m0 + wr * 64 + mi * 16 + g * 4 + r;
        const int col = n0 + wc * 64 + ni * 16 + c;
        const float v = acc[mi][ni][r] + bv[ni];
        if (OUT_F32) ((float*)Cout)[(size_t)row * N + col] = v;
        else         ((u16*)Cout)[(size_t)row * N + col] = f2bf(v);
      }
}

// ---------------------------------------------------------------------------
// 4. reshape + RoPE.  mode 0: Q, mode 1: K  ([B,S,H,dk] -> RoPE -> [B,H,S,dk])
//    mode 2: V  ([B,S,H,dk] -> [B,H,dk,S] transposed via padded LDS tile)
// ---------------------------------------------------------------------------
__global__ void reshape_rope(const u16* __restrict__ qp, const u16* __restrict__ kp,
                             const u16* __restrict__ vp,
                             const float* __restrict__ cost, const float* __restrict__ sint,
                             u16* __restrict__ Qh, u16* __restrict__ Kh, u16* __restrict__ Vtr,
                             int B, int H, int S) {
  __shared__ u16 tile[64][66];   // +2 pad -> conflict-light transpose
  const int mode = blockIdx.z;
  const int bh = blockIdx.y;
  const int b = bh / H, h = bh % H;
  const int s0 = blockIdx.x * 64;
  const int t = threadIdx.x;
  const int D = H * 64;

  if (mode < 2) {
    const u16* src = mode ? kp : qp;
    u16* dst = mode ? Kh : Qh;
    const int s = s0 + (t >> 2);
    const int dc = (t & 3) * 8;                  // 8 d-elems in lower half [0,32)
    const u16* pr = src + (size_t)(b * S + s) * D + h * 64;
    const short8 lo = *(const short8*)(pr + dc);
    const short8 hi = *(const short8*)(pr + dc + 32);
    short8 olo, ohi;
#pragma unroll
    for (int j = 0; j < 8; ++j) {
      const float co = cost[s * 32 + dc + j];
      const float si = sint[s * 32 + dc + j];
      const float x1 = bf2f(lo[j]);
      const float x2 = bf2f(hi[j]);
      olo[j] = (short)f2bf(x1 * co - x2 * si);
      ohi[j] = (short)f2bf(x2 * co + x1 * si);
    }
    u16* op = dst + ((size_t)bh * S + s) * 64;
    *(short8*)(op + dc) = olo;
    *(short8*)(op + dc + 32) = ohi;
  } else {
#pragma unroll
    for (int it = 0; it < 2; ++it) {
      const int chunk = it * 256 + t;
      const int s = chunk >> 3;
      const int dc = (chunk & 7) * 8;
      const short8 v = *(const short8*)(vp + (size_t)(b * S + s0 + s) * D + h * 64 + dc);
#pragma unroll
      for (int u = 0; u < 8; ++u) tile[s][dc + u] = (u16)v[u];
    }
    __syncthreads();
    const int d = t >> 2;
    const int sc = (t & 3) * 16;
    u16* op = Vtr + ((size_t)bh * 64 + d) * S + s0 + sc;
    short8 v0, v1;
#pragma unroll
    for (int j = 0; j < 8; ++j) v0[j] = (short)tile[sc + j][d];
#pragma unroll
    for (int j = 0; j < 8; ++j) v1[j] = (short)tile[sc + 8 + j][d];
    *(short8*)op = v0;
    *(short8*)(op + 8) = v1;
  }
}

// ---------------------------------------------------------------------------
// 5. causal flash attention.
//   grid (S/64, B*H), 256 thr. Wave w owns q rows [q0+16w, q0+16w+16).
//   K tile [64 keys][64 d] and V^T tile [64 d][64 keys] staged via
//   global_load_lds with the same XOR-swizzle as the GEMM.
//   Scores D[q][k]: A=Q frag (m=lane&15), B=K frag. Online softmax per row
//   (4 regs/lane; 16-lane shfl_xor reduce). P staged bf16 through per-wave
//   swizzled LDS -> A-frag for PV.
// ---------------------------------------------------------------------------
__global__ __launch_bounds__(256, 2)
void attn_kernel(const u16* __restrict__ Qh, const u16* __restrict__ Kh,
                 const u16* __restrict__ Vt, u16* __restrict__ ctx,
                 int B, int H, int S) {
  __shared__ u16 Ks[64 * 64];
  __shared__ u16 Vs[64 * 64];
  __shared__ u16 Ps[4][16 * 64];
  const int tid = threadIdx.x, wid = tid >> 6, lane = tid & 63;
  const int g = lane >> 4, c = lane & 15;
  const int bh = blockIdx.y;
  const int q0 = blockIdx.x * 64;
  const size_t baseQK = (size_t)bh * S * 64;
  const size_t baseV = (size_t)bh * 64 * S;

  short8 qf[2];
  {
    const u16* qptr = Qh + baseQK + (size_t)(q0 + wid * 16 + c) * 64 + g * 8;
    qf[0] = *(const short8*)qptr;
    qf[1] = *(const short8*)(qptr + 32);
  }
  float m_run[4], l_run[4];
  f32x4 o[4];
#pragma unroll
  for (int r = 0; r < 4; ++r) { m_run[r] = -__builtin_inff(); l_run[r] = 0.0f; }
#pragma unroll
  for (int nf = 0; nf < 4; ++nf) o[nf] = (f32x4)(0.0f);

  const int ktiles = blockIdx.x + 1;             // causal: kt*64 <= q0+63
  for (int kt = 0; kt < ktiles; ++kt) {
    // stage K tile + V^T tile (512 chunks each -> 2 issues x 256 thr)
#pragma unroll
    for (int i = 0; i < 2; ++i) {
      const int chunk = i * 256 + tid;
      const int row = chunk >> 3;
      const int scz = (chunk & 7) ^ (row & 7);
      gload_lds16(Kh + baseQK + (size_t)(kt * 64 + row) * 64 + scz * 8,
                  (char*)Ks + (size_t)(i * 256 + (wid << 6)) * 16);
      gload_lds16(Vt + baseV + (size_t)row * S + (kt * 64 + scz * 8),
                  (char*)Vs + (size_t)(i * 256 + (wid << 6)) * 16);
    }
    __syncthreads();

    // scores: 16 q x 64 k per wave
    f32x4 sc4[4];
#pragma unroll
    for (int nf = 0; nf < 4; ++nf) {
      f32x4 a = (f32x4)(0.0f);
#pragma unroll
      for (int ks = 0; ks < 2; ++ks) {
        const int row = nf * 16 + c;
        const int cch = (g + ks * 4) ^ (row & 7);
        const short8 kf = *(const short8*)((const char*)Ks + row * 128 + cch * 16);
        a = __builtin_amdgcn_mfma_f32_16x16x32_bf16(qf[ks], kf, a, 0, 0, 0);
      }
      sc4[nf] = a;
    }

    float p[4][4];
    const bool diag = (kt == blockIdx.x);
#pragma unroll
    for (int nf = 0; nf < 4; ++nf)
#pragma unroll
      for (int r = 0; r < 4; ++r) {
        float v = sc4[nf][r] * 0.125f;           // 1/sqrt(64)
        if (diag) {
          const int qq = q0 + wid * 16 + g * 4 + r;
          const int kk = kt * 64 + nf * 16 + c;
          if (kk > qq) v = -__builtin_inff();
        }
        p[nf][r] = v;
      }

    // online softmax (rows live in reg r, replicated over the 16 c-lanes)
#pragma unroll
    for (int r = 0; r < 4; ++r) {
      float pm = fmaxf(fmaxf(p[0][r], p[1][r]), fmaxf(p[2][r], p[3][r]));
      pm = fmaxf(pm, __shfl_xor(pm, 1));
      pm = fmaxf(pm, __shfl_xor(pm, 2));
      pm = fmaxf(pm, __shfl_xor(pm, 4));
      pm = fmaxf(pm, __shfl_xor(pm, 8));
      const float mnew = fmaxf(m_run[r], pm);
      const float rs = __builtin_exp2f((m_run[r] - mnew) * LOG2E);
      m_run[r] = mnew;
      float psum = 0.0f;
#pragma unroll
      for (int nf = 0; nf < 4; ++nf) {
        p[nf][r] = __builtin_exp2f((p[nf][r] - mnew) * LOG2E);
        psum += p[nf][r];
      }
      psum += __shfl_xor(psum, 1);
      psum += __shfl_xor(psum, 2);
      psum += __shfl_xor(psum, 4);
      psum += __shfl_xor(psum, 8);
      l_run[r] = l_run[r] * rs + psum;
#pragma unroll
      for (int nf = 0; nf < 4; ++nf) o[nf][r] *= rs;
    }

    // P -> per-wave swizzled LDS -> A-frags
    u16* pw = &Ps[wid][0];
#pragma unroll
    for (int nf = 0; nf < 4; ++nf)
#pragma unroll
      for (int r = 0; r < 4; ++r) {
        const int row = g * 4 + r;
        const int col = nf * 16 + c;
        pw[row * 64 + (col ^ ((row & 7) << 3))] = f2bf(p[nf][r]);
      }
    short8 pa[2];
#pragma unroll
    for (int ks = 0; ks < 2; ++ks) {
      const int cch = (g + ks * 4) ^ (c & 7);
      pa[ks] = *(const short8*)((const char*)pw + c * 128 + cch * 16);
    }
    // PV: o[q][d] += P[q][k] V[k][d]
#pragma unroll
    for (int nf = 0; nf < 4; ++nf)
#pragma unroll
      for (int ks = 0; ks < 2; ++ks) {
        const int vrow = nf * 16 + c;
        const int cch = (g + ks * 4) ^ (vrow & 7);
        const short8 vf = *(const short8*)((const char*)Vs + vrow * 128 + cch * 16);
        o[nf] = __builtin_amdgcn_mfma_f32_16x16x32_bf16(pa[ks], vf, o[nf], 0, 0, 0);
      }
    __syncthreads();
  }

  // normalize + write ctx (token-major [B*S, D] for the O-projection)
  const int b = bh >> 4, h = bh & 15;
#pragma unroll
  for (int r = 0; r < 4; ++r) {
    const float inv = 1.0f / l_run[r];
    const size_t rowoff = (size_t)(b * S + q0 + wid * 16 + g * 4 + r) * (size_t)(H * 64) + h * 64;
#pragma unroll
    for (int nf = 0; nf < 4; ++nf)
      ctx[rowoff + nf * 16 + c] = f2bf(o[nf][r] * inv);
  }
}

// ---------------------------------------------------------------------------
extern "C" void kernel_launch(void* const* d_in, const int* in_sizes, int n_in,
                              void* d_out, int out_size, void* d_ws, size_t ws_size,
                              hipStream_t stream) {
  const float* query = (const float*)d_in[0];
  const float* key   = (const float*)d_in[1];
  const float* value = (const float*)d_in[2];
  const float* W_q = (const float*)d_in[3];
  const float* b_q = (const float*)d_in[4];
  const float* W_k = (const float*)d_in[5];
  const float* b_k = (const float*)d_in[6];
  const float* W_v = (const float*)d_in[7];
  const float* b_v = (const float*)d_in[8];
  const float* W_o = (const float*)d_in[9];
  const float* b_o = (const float*)d_in[10];

  const int D = 1024, H = 16, S = 2048;
  const int BS = in_sizes[0] / D;          // B * S = 8192
  const int B = BS / S;

  // workspace layout (u16 units), with aliasing:
  //   xq/xk/xv reused as Qh/Kh/Vtr after QKV GEMMs; qp reused as ctx.
  const size_t nX = (size_t)BS * D;        // 8.4M elems
  const size_t nW = (size_t)D * D;
  u16* p = (u16*)d_ws;
  u16* xq = p;  p += nX;
  u16* xk = p;  p += nX;
  u16* xv = p;  p += nX;
  u16* wq = p;  p += nW;
  u16* wk = p;  p += nW;
  u16* wv = p;  p += nW;
  u16* wo = p;  p += nW;
  u16* qp = p;  p += nX;
  u16* kp = p;  p += nX;
  u16* vp = p;  p += nX;
  float* cost = (float*)p;
  float* sint = cost + (size_t)S * 32;
  u16* Qh = xq;    // alias: xq dead after Q GEMM
  u16* Kh = xk;    // alias: xk dead after K GEMM
  u16* Vtr = xv;   // alias: xv dead after V GEMM
  u16* ctx = qp;   // alias: qp dead after reshape_rope

  auto cvt = [&](const float* in, u16* out, size_t n) {
    int n4 = (int)(n / 4);
    int blocks = (n4 + 255) / 256; if (blocks > 2048) blocks = 2048;
    cvt_f32_to_bf16<<<blocks, 256, 0, stream>>>(in, out, n4);
  };
  cvt(query, xq, nX);
  cvt(key,   xk, nX);
  cvt(value, xv, nX);
  cvt(W_q, wq, nW);
  cvt(W_k, wk, nW);
  cvt(W_v, wv, nW);
  cvt(W_o, wo, nW);

  rope_tables<<<(S * 32 + 255) / 256, 256, 0, stream>>>(cost, sint, S);

  const dim3 gg(BS / 128, D / 128);
  gemm_bt<0><<<gg, 256, 0, stream>>>(xq, wq, b_q, qp, BS, D, D);
  gemm_bt<0><<<gg, 256, 0, stream>>>(xk, wk, b_k, kp, BS, D, D);
  gemm_bt<0><<<gg, 256, 0, stream>>>(xv, wv, b_v, vp, BS, D, D);

  reshape_rope<<<dim3(S / 64, B * H, 3), 256, 0, stream>>>(qp, kp, vp, cost, sint,
                                                           Qh, Kh, Vtr, B, H, S);

  attn_kernel<<<dim3(S / 64, B * H), 256, 0, stream>>>(Qh, Kh, Vtr, ctx, B, H, S);

  gemm_bt<1><<<gg, 256, 0, stream>>>(ctx, wo, b_o, d_out, BS, D, D);
}

// Round 4
// 363.250 us; speedup vs baseline: 1.3738x; 1.3738x over previous
//
#include <hip/hip_runtime.h>
#include <hip/hip_bf16.h>
#include <cstdint>
#include <cstddef>

// ---------------------------------------------------------------------------
// MultiHeadAttention fused pipeline, bf16 MFMA compute.
//   B=4, S=2048, D=1024, H=16, dk=64
// Stages:
//   1. cvt fp32->bf16 for x_q/x_k/x_v and W_q/W_k/W_v/W_o
//   2. rope cos/sin tables  [S][32] fp32
//   3. GEMM (bf16 out): qp/kp/vp = X @ W^T + b   (token-major [B*S, D])
//   4. reshape: Q,K -> RoPE -> [B,H,S,dk] (Q pre-scaled by 0.125*log2e);
//      V -> [B,H,dk,S] (transposed)
//   5. flash attention (causal, online softmax, swapped-operand MFMA,
//      fold-paired blocks, double-buffered staging) -> ctx bf16 [B*S, D]
//   6. GEMM (f32 out): out = ctx @ W_o^T + b_o
// ---------------------------------------------------------------------------

typedef __attribute__((ext_vector_type(8))) short short8;   // 8 x bf16 (4 VGPR)
typedef __attribute__((ext_vector_type(4))) float f32x4;    // MFMA C/D frag
typedef unsigned short u16;

#define LOG2E 1.44269504088896340736f
#define SCALE_Q 0.18033688011112042f   /* 0.125 * log2(e): scores in exp2 domain */

__device__ __forceinline__ u16 f2bf(float f) {
  __hip_bfloat16 h = __float2bfloat16(f);
  return *reinterpret_cast<u16*>(&h);
}
__device__ __forceinline__ float bf2f(short bits) {
  unsigned int u = ((unsigned int)(u16)bits) << 16;
  return __uint_as_float(u);
}
__device__ __forceinline__ void gload_lds16(const void* g, void* l) {
  __builtin_amdgcn_global_load_lds(
      (const __attribute__((address_space(1))) void*)g,
      (__attribute__((address_space(3))) void*)l, 16, 0, 0);
}
__device__ __forceinline__ f32x4 max4(f32x4 a, f32x4 b) {
  f32x4 r;
  r[0] = fmaxf(a[0], b[0]); r[1] = fmaxf(a[1], b[1]);
  r[2] = fmaxf(a[2], b[2]); r[3] = fmaxf(a[3], b[3]);
  return r;
}

// ---------------------------------------------------------------------------
// 1. fp32 -> bf16 convert
// ---------------------------------------------------------------------------
__global__ void cvt_f32_to_bf16(const float* __restrict__ in, u16* __restrict__ out, int n4) {
  const int stride = gridDim.x * blockDim.x;
  for (int i = blockIdx.x * blockDim.x + threadIdx.x; i < n4; i += stride) {
    const float4 v = ((const float4*)in)[i];
    ushort4 o;
    o.x = f2bf(v.x); o.y = f2bf(v.y); o.z = f2bf(v.z); o.w = f2bf(v.w);
    ((ushort4*)out)[i] = o;
  }
}

// ---------------------------------------------------------------------------
// 2. RoPE tables
// ---------------------------------------------------------------------------
__global__ void rope_tables(float* __restrict__ cost, float* __restrict__ sint, int S) {
  const int idx = blockIdx.x * blockDim.x + threadIdx.x;
  if (idx >= S * 32) return;
  const int s = idx >> 5, i = idx & 31;
  const float invf = powf(10000.0f, -(float)i * (1.0f / 32.0f));
  const float ang = (float)s * invf;
  cost[idx] = cosf(ang);
  sint[idx] = sinf(ang);
}

// ---------------------------------------------------------------------------
// 3/6. GEMM  C[M,N] = A[M,K] @ Bt[N,K]^T + bias
// ---------------------------------------------------------------------------
template<int OUT_F32>
__global__ __launch_bounds__(256, 2)
void gemm_bt(const u16* __restrict__ A, const u16* __restrict__ Bt,
             const float* __restrict__ bias, void* __restrict__ Cout,
             int M, int N, int K) {
  __shared__ u16 As[128 * 64];
  __shared__ u16 Bs[128 * 64];
  const int tid = threadIdx.x;
  const int wid = tid >> 6;
  const int lane = tid & 63;
  const int g = lane >> 4, c = lane & 15;
  const int m0 = blockIdx.x * 128;
  const int n0 = blockIdx.y * 128;
  const int wr = wid >> 1, wc = wid & 1;

  f32x4 acc[4][4];
#pragma unroll
  for (int i = 0; i < 4; ++i)
#pragma unroll
    for (int j = 0; j < 4; ++j) acc[i][j] = (f32x4)(0.0f);

  const int kIters = K >> 6;
  for (int kt = 0; kt < kIters; ++kt) {
    const int k0 = kt << 6;
#pragma unroll
    for (int i = 0; i < 4; ++i) {
      const int chunk = i * 256 + tid;
      const int row = chunk >> 3;
      const int scz = (chunk & 7) ^ (row & 7);
      gload_lds16(A + (size_t)(m0 + row) * K + (k0 + scz * 8),
                  (char*)As + (size_t)(i * 256 + (wid << 6)) * 16);
      gload_lds16(Bt + (size_t)(n0 + row) * K + (k0 + scz * 8),
                  (char*)Bs + (size_t)(i * 256 + (wid << 6)) * 16);
    }
    __syncthreads();
#pragma unroll
    for (int ks = 0; ks < 2; ++ks) {
      short8 af[4], bfr[4];
#pragma unroll
      for (int mi = 0; mi < 4; ++mi) {
        const int row = wr * 64 + mi * 16 + c;
        const int cch = (g + ks * 4) ^ (row & 7);
        af[mi] = *(const short8*)((const char*)As + row * 128 + cch * 16);
      }
#pragma unroll
      for (int ni = 0; ni < 4; ++ni) {
        const int row = wc * 64 + ni * 16 + c;
        const int cch = (g + ks * 4) ^ (row & 7);
        bfr[ni] = *(const short8*)((const char*)Bs + row * 128 + cch * 16);
      }
#pragma unroll
      for (int mi = 0; mi < 4; ++mi)
#pragma unroll
        for (int ni = 0; ni < 4; ++ni)
          acc[mi][ni] = __builtin_amdgcn_mfma_f32_16x16x32_bf16(af[mi], bfr[ni], acc[mi][ni], 0, 0, 0);
    }
    __syncthreads();
  }

  float bv[4];
#pragma unroll
  for (int ni = 0; ni < 4; ++ni) bv[ni] = bias[n0 + wc * 64 + ni * 16 + c];

#pragma unroll
  for (int mi = 0; mi < 4; ++mi)
#pragma unroll
    for (int ni = 0; ni < 4; ++ni)
#pragma unroll
      for (int r = 0; r < 4; ++r) {
        const int row = m0 + wr * 64 + mi * 16 + g * 4 + r;
        const int col = n0 + wc * 64 + ni * 16 + c;
        const float v = acc[mi][ni][r] + bv[ni];
        if (OUT_F32) ((float*)Cout)[(size_t)row * N + col] = v;
        else         ((u16*)Cout)[(size_t)row * N + col] = f2bf(v);
      }
}

// ---------------------------------------------------------------------------
// 4. reshape + RoPE.  mode 0: Q (scaled by SCALE_Q), mode 1: K, mode 2: V^T
// ---------------------------------------------------------------------------
__global__ void reshape_rope(const u16* __restrict__ qp, const u16* __restrict__ kp,
                             const u16* __restrict__ vp,
                             const float* __restrict__ cost, const float* __restrict__ sint,
                             u16* __restrict__ Qh, u16* __restrict__ Kh, u16* __restrict__ Vtr,
                             int B, int H, int S) {
  __shared__ u16 tile[64][66];
  const int mode = blockIdx.z;
  const int bh = blockIdx.y;
  const int b = bh / H, h = bh % H;
  const int s0 = blockIdx.x * 64;
  const int t = threadIdx.x;
  const int D = H * 64;

  if (mode < 2) {
    const u16* src = mode ? kp : qp;
    u16* dst = mode ? Kh : Qh;
    const float qs = mode ? 1.0f : SCALE_Q;
    const int s = s0 + (t >> 2);
    const int dc = (t & 3) * 8;
    const u16* pr = src + (size_t)(b * S + s) * D + h * 64;
    const short8 lo = *(const short8*)(pr + dc);
    const short8 hi = *(const short8*)(pr + dc + 32);
    short8 olo, ohi;
#pragma unroll
    for (int j = 0; j < 8; ++j) {
      const float co = cost[s * 32 + dc + j];
      const float si = sint[s * 32 + dc + j];
      const float x1 = bf2f(lo[j]);
      const float x2 = bf2f(hi[j]);
      olo[j] = (short)f2bf((x1 * co - x2 * si) * qs);
      ohi[j] = (short)f2bf((x2 * co + x1 * si) * qs);
    }
    u16* op = dst + ((size_t)bh * S + s) * 64;
    *(short8*)(op + dc) = olo;
    *(short8*)(op + dc + 32) = ohi;
  } else {
#pragma unroll
    for (int it = 0; it < 2; ++it) {
      const int chunk = it * 256 + t;
      const int s = chunk >> 3;
      const int dc = (chunk & 7) * 8;
      const short8 v = *(const short8*)(vp + (size_t)(b * S + s0 + s) * D + h * 64 + dc);
#pragma unroll
      for (int u = 0; u < 8; ++u) tile[s][dc + u] = (u16)v[u];
    }
    __syncthreads();
    const int d = t >> 2;
    const int sc = (t & 3) * 16;
    u16* op = Vtr + ((size_t)bh * 64 + d) * S + s0 + sc;
    short8 v0, v1;
#pragma unroll
    for (int j = 0; j < 8; ++j) v0[j] = (short)tile[sc + j][d];
#pragma unroll
    for (int j = 0; j < 8; ++j) v1[j] = (short)tile[sc + 8 + j][d];
    *(short8*)op = v0;
    *(short8*)(op + 8) = v1;
  }
}

// ---------------------------------------------------------------------------
// 5. causal flash attention, v2.
//   Swapped-operand MFMA: Sc^T = K x Q^T (lane owns q-columns), O^T = V^T x P^T
//   (rescale is lane-local). 4 waves x 32 q-rows = 128 q/block.
//   Fold-pairing: block bx does super-tiles bx and NST-1-bx -> uniform 36
//   k-tiles/block. Double-buffered K/V staging (2-phase). XCD-clustered remap.
//   Scores arrive in exp2 domain (Q pre-scaled); defer-max THR=8.
// ---------------------------------------------------------------------------
__global__ __launch_bounds__(256, 3)
void attn_kernel(const u16* __restrict__ Qh, const u16* __restrict__ Kh,
                 const u16* __restrict__ Vt, u16* __restrict__ ctx,
                 int B, int H, int S) {
  __shared__ u16 KV[2][2][64 * 64];   // [buf][K=0/V=1], 32 KiB
  __shared__ u16 Ps[4][16 * 64];      // per-wave P tile (reused per qf), 8 KiB
  const int tid = threadIdx.x, wid = tid >> 6, lane = tid & 63;
  const int g = lane >> 4, c = lane & 15;

  // XCD-clustered remap: consecutive bh share one XCD's L2
  const int nstH = gridDim.x;              // NST/2
  const int nwg = nstH * gridDim.y;
  const int lin = blockIdx.x + nstH * blockIdx.y;
  const int tt = (lin & 7) * (nwg >> 3) + (lin >> 3);
  const int bx = tt % nstH;
  const int bh = tt / nstH;
  const int b = bh / H, h = bh % H;
  const int D = H * 64;
  const int NST = nstH * 2;

  const size_t baseQK = (size_t)bh * S * 64;
  const size_t baseV  = (size_t)bh * 64 * S;

  for (int ph = 0; ph < 2; ++ph) {
    const int stile = ph ? (NST - 1 - bx) : bx;
    const int q0 = stile * 128;
    const int KT = (q0 >> 6) + 2;          // causal k-tiles for this super-tile
    const int q0w = q0 + wid * 32;
    const int ktl = (q0w + 31) >> 6;       // wave's last (partial) k-tile
    const int qg0 = q0w + c, qg1 = q0w + 16 + c;

    // Q B-frags, hoisted: lane holds Q[q0w+qf*16+c][32*ks+8*g .. +8)
    short8 qB[2][2];
#pragma unroll
    for (int qf = 0; qf < 2; ++qf)
#pragma unroll
      for (int ks = 0; ks < 2; ++ks)
        qB[qf][ks] = *(const short8*)(Qh + baseQK +
                       (size_t)(q0w + qf * 16 + c) * 64 + ks * 32 + g * 8);

    float m_r[2], l_r[2];
    m_r[0] = m_r[1] = -__builtin_inff();
    l_r[0] = l_r[1] = 0.0f;
    f32x4 o[4][2];
#pragma unroll
    for (int df = 0; df < 4; ++df) { o[df][0] = (f32x4)(0.0f); o[df][1] = (f32x4)(0.0f); }

    auto stage = [&](int buf, int kt) {
#pragma unroll
      for (int i = 0; i < 2; ++i) {
        const int chunk = i * 256 + tid;
        const int row = chunk >> 3;
        const int scz = (chunk & 7) ^ (row & 7);
        gload_lds16(Kh + baseQK + (size_t)(kt * 64 + row) * 64 + scz * 8,
                    (char*)&KV[buf][0][0] + (size_t)(i * 256 + (wid << 6)) * 16);
        gload_lds16(Vt + baseV + (size_t)row * S + (kt * 64 + scz * 8),
                    (char*)&KV[buf][1][0] + (size_t)(i * 256 + (wid << 6)) * 16);
      }
    };

    stage(0, 0);
    __syncthreads();
    int cur = 0;
    for (int kt = 0; kt < KT; ++kt) {
      if (kt + 1 < KT) stage(cur ^ 1, kt + 1);   // 2-phase prefetch
      if (kt <= ktl) {                            // wave-uniform causal skip
        const char* Kb = (const char*)&KV[cur][0][0];
        const char* Vb = (const char*)&KV[cur][1][0];

        // QK^T (swapped): sc[kf][qf] = D[k=kf*16+4g+r][q=qf*16+c]
        f32x4 sc[4][2];
#pragma unroll
        for (int kf = 0; kf < 4; ++kf) { sc[kf][0] = (f32x4)(0.0f); sc[kf][1] = (f32x4)(0.0f); }
#pragma unroll
        for (int ks = 0; ks < 2; ++ks) {
          short8 kA[4];
#pragma unroll
          for (int kf = 0; kf < 4; ++kf) {
            const int row = kf * 16 + c;
            kA[kf] = *(const short8*)(Kb + row * 128 + (((g + 4 * ks) ^ (row & 7))) * 16);
          }
#pragma unroll
          for (int kf = 0; kf < 4; ++kf) {
            sc[kf][0] = __builtin_amdgcn_mfma_f32_16x16x32_bf16(kA[kf], qB[0][ks], sc[kf][0], 0, 0, 0);
            sc[kf][1] = __builtin_amdgcn_mfma_f32_16x16x32_bf16(kA[kf], qB[1][ks], sc[kf][1], 0, 0, 0);
          }
        }

        if (kt == ktl) {   // only the last tile is causally partial
#pragma unroll
          for (int kf = 0; kf < 4; ++kf)
#pragma unroll
            for (int r = 0; r < 4; ++r) {
              const int kg = kt * 64 + kf * 16 + 4 * g + r;
              if (kg > qg0) sc[kf][0][r] = -__builtin_inff();
              if (kg > qg1) sc[kf][1][r] = -__builtin_inff();
            }
        }

        u16* Pw = &Ps[wid][0];
        short8 pB[2][2];
#pragma unroll
        for (int qf = 0; qf < 2; ++qf) {
          // row max: 15 in-lane + 2 shfl (lanes c,c+16,c+32,c+48 share q)
          f32x4 mm = max4(max4(sc[0][qf], sc[1][qf]), max4(sc[2][qf], sc[3][qf]));
          float pm = fmaxf(fmaxf(mm[0], mm[1]), fmaxf(mm[2], mm[3]));
          pm = fmaxf(pm, __shfl_xor(pm, 16));
          pm = fmaxf(pm, __shfl_xor(pm, 32));
          // defer-max (THR=8 in exp2 domain -> P bounded by 256)
          if (__any(pm > m_r[qf] + 8.0f)) {
            const float mn = fmaxf(m_r[qf], pm);
            const float rs = __builtin_exp2f(m_r[qf] - mn);
            m_r[qf] = mn; l_r[qf] *= rs;
#pragma unroll
            for (int df = 0; df < 4; ++df) o[df][qf] *= rs;
          }
          f32x4 ps4 = (f32x4)(0.0f);
#pragma unroll
          for (int kf = 0; kf < 4; ++kf) {
            f32x4 pv;
#pragma unroll
            for (int r = 0; r < 4; ++r) pv[r] = __builtin_exp2f(sc[kf][qf][r] - m_r[qf]);
            sc[kf][qf] = pv;
            ps4 += pv;
          }
          float psum = (ps4[0] + ps4[1]) + (ps4[2] + ps4[3]);
          psum += __shfl_xor(psum, 16);
          psum += __shfl_xor(psum, 32);
          l_r[qf] += psum;

          // P -> per-wave LDS (b64 writes, swizzled), then P^T B-frags
#pragma unroll
          for (int kf = 0; kf < 4; ++kf) {
            ushort4 pk;
            pk.x = f2bf(sc[kf][qf][0]); pk.y = f2bf(sc[kf][qf][1]);
            pk.z = f2bf(sc[kf][qf][2]); pk.w = f2bf(sc[kf][qf][3]);
            *(ushort4*)((char*)Pw + c * 128 +
                        (((2 * kf + (g >> 1)) ^ (c & 7))) * 16 + 8 * (g & 1)) = pk;
          }
#pragma unroll
          for (int ks = 0; ks < 2; ++ks)
            pB[qf][ks] = *(const short8*)((const char*)Pw + c * 128 +
                                          (((g + 4 * ks) ^ (c & 7))) * 16);
        }

        // PV (swapped): o[df][qf] = D[d=df*16+4g+r][q=qf*16+c]
#pragma unroll
        for (int ks = 0; ks < 2; ++ks)
#pragma unroll
          for (int df = 0; df < 4; ++df) {
            const int row = df * 16 + c;
            const short8 va = *(const short8*)(Vb + row * 128 + (((g + 4 * ks) ^ (row & 7))) * 16);
            o[df][0] = __builtin_amdgcn_mfma_f32_16x16x32_bf16(va, pB[0][ks], o[df][0], 0, 0, 0);
            o[df][1] = __builtin_amdgcn_mfma_f32_16x16x32_bf16(va, pB[1][ks], o[df][1], 0, 0, 0);
          }
      }
      __syncthreads();
      cur ^= 1;
    }

    // epilogue: O^T -> ctx token-major; lane owns rows q (qf*16+c), d runs of 4
#pragma unroll
    for (int qf = 0; qf < 2; ++qf) {
      const float inv = 1.0f / l_r[qf];
      u16* rowp = ctx + (size_t)(b * S + q0w + qf * 16 + c) * D + h * 64;
#pragma unroll
      for (int df = 0; df < 4; ++df) {
        ushort4 w;
        w.x = f2bf(o[df][qf][0] * inv); w.y = f2bf(o[df][qf][1] * inv);
        w.z = f2bf(o[df][qf][2] * inv); w.w = f2bf(o[df][qf][3] * inv);
        *(ushort4*)(rowp + df * 16 + 4 * g) = w;
      }
    }
  }
}

// ---------------------------------------------------------------------------
extern "C" void kernel_launch(void* const* d_in, const int* in_sizes, int n_in,
                              void* d_out, int out_size, void* d_ws, size_t ws_size,
                              hipStream_t stream) {
  const float* query = (const float*)d_in[0];
  const float* key   = (const float*)d_in[1];
  const float* value = (const float*)d_in[2];
  const float* W_q = (const float*)d_in[3];
  const float* b_q = (const float*)d_in[4];
  const float* W_k = (const float*)d_in[5];
  const float* b_k = (const float*)d_in[6];
  const float* W_v = (const float*)d_in[7];
  const float* b_v = (const float*)d_in[8];
  const float* W_o = (const float*)d_in[9];
  const float* b_o = (const float*)d_in[10];

  const int D = 1024, H = 16, S = 2048;
  const int BS = in_sizes[0] / D;          // B * S = 8192
  const int B = BS / S;

  const size_t nX = (size_t)BS * D;
  const size_t nW = (size_t)D * D;
  u16* p = (u16*)d_ws;
  u16* xq = p;  p += nX;
  u16* xk = p;  p += nX;
  u16* xv = p;  p += nX;
  u16* wq = p;  p += nW;
  u16* wk = p;  p += nW;
  u16* wv = p;  p += nW;
  u16* wo = p;  p += nW;
  u16* qp = p;  p += nX;
  u16* kp = p;  p += nX;
  u16* vp = p;  p += nX;
  float* cost = (float*)p;
  float* sint = cost + (size_t)S * 32;
  u16* Qh = xq;    // alias: xq dead after Q GEMM
  u16* Kh = xk;    // alias: xk dead after K GEMM
  u16* Vtr = xv;   // alias: xv dead after V GEMM
  u16* ctx = qp;   // alias: qp dead after reshape_rope

  auto cvt = [&](const float* in, u16* out, size_t n) {
    int n4 = (int)(n / 4);
    int blocks = (n4 + 255) / 256; if (blocks > 2048) blocks = 2048;
    cvt_f32_to_bf16<<<blocks, 256, 0, stream>>>(in, out, n4);
  };
  cvt(query, xq, nX);
  cvt(key,   xk, nX);
  cvt(value, xv, nX);
  cvt(W_q, wq, nW);
  cvt(W_k, wk, nW);
  cvt(W_v, wv, nW);
  cvt(W_o, wo, nW);

  rope_tables<<<(S * 32 + 255) / 256, 256, 0, stream>>>(cost, sint, S);

  const dim3 gg(BS / 128, D / 128);
  gemm_bt<0><<<gg, 256, 0, stream>>>(xq, wq, b_q, qp, BS, D, D);
  gemm_bt<0><<<gg, 256, 0, stream>>>(xk, wk, b_k, kp, BS, D, D);
  gemm_bt<0><<<gg, 256, 0, stream>>>(xv, wv, b_v, vp, BS, D, D);

  reshape_rope<<<dim3(S / 64, B * H, 3), 256, 0, stream>>>(qp, kp, vp, cost, sint,
                                                           Qh, Kh, Vtr, B, H, S);

  attn_kernel<<<dim3(S / 256, B * H), 256, 0, stream>>>(Qh, Kh, Vtr, ctx, B, H, S);

  gemm_bt<1><<<gg, 256, 0, stream>>>(ctx, wo, b_o, d_out, BS, D, D);
}

// Round 6
// 334.060 us; speedup vs baseline: 1.4938x; 1.0874x over previous
//
#include <hip/hip_runtime.h>
#include <hip/hip_bf16.h>
#include <cstdint>
#include <cstddef>

// ---------------------------------------------------------------------------
// MultiHeadAttention fused pipeline, bf16 MFMA compute.
//   B=4, S=2048, D=1024, H=16, dk=64
// Stages:
//   1. cvt_all: one kernel converts q/k/v activations + 4 weights fp32->bf16
//   2. rope tables [S][32]
//   3. gemm_fused<0/1/2>: QKV projection GEMMs with fused epilogues:
//        0: +bias -> RoPE -> *0.125*log2e -> Qh [bh][s][dk]
//        1: +bias -> RoPE ->                Kh [bh][s][dk]
//        2: +bias -> transpose           -> Vtr [bh][dk][s]
//      (RoPE pair (d, d+32) == acc pair (ni, ni+2): thread-local, fp32)
//   4. flash attention (causal, swapped-operand MFMA, fold-paired blocks,
//      double-buffered staging, defer-max) -> ctx bf16 [B*S, D]
//   5. gemm_fused<3>: out = ctx @ W_o^T + b_o (f32, token-major)
// GEMM grid: 1D 512 with XCD-chunked remap (m-panel group per XCD L2).
// ---------------------------------------------------------------------------

typedef __attribute__((ext_vector_type(8))) short short8;   // 8 x bf16 (4 VGPR)
typedef __attribute__((ext_vector_type(4))) float f32x4;    // MFMA C/D frag
typedef unsigned short u16;

#define SCALE_Q 0.18033688011112042f   /* 0.125 * log2(e): scores in exp2 domain */

__device__ __forceinline__ u16 f2bf(float f) {
  __hip_bfloat16 h = __float2bfloat16(f);
  return *reinterpret_cast<u16*>(&h);
}
__device__ __forceinline__ float bf2f(short bits) {
  unsigned int u = ((unsigned int)(u16)bits) << 16;
  return __uint_as_float(u);
}
__device__ __forceinline__ void gload_lds16(const void* g, void* l) {
  __builtin_amdgcn_global_load_lds(
      (const __attribute__((address_space(1))) void*)g,
      (__attribute__((address_space(3))) void*)l, 16, 0, 0);
}
__device__ __forceinline__ f32x4 max4(f32x4 a, f32x4 b) {
  f32x4 r;
  r[0] = fmaxf(a[0], b[0]); r[1] = fmaxf(a[1], b[1]);
  r[2] = fmaxf(a[2], b[2]); r[3] = fmaxf(a[3], b[3]);
  return r;
}

// ---------------------------------------------------------------------------
// 1. one-shot fp32 -> bf16 convert, 7 jobs
// ---------------------------------------------------------------------------
struct CvtJobs {
  const float* src[7];
  u16* dst[7];
  int pref[8];   // prefix sums in float4 units
};

__global__ void cvt_all(CvtJobs jobs, int total4) {
  const int stride = gridDim.x * blockDim.x;
  for (int i = blockIdx.x * blockDim.x + threadIdx.x; i < total4; i += stride) {
    int j = 0;
#pragma unroll
    for (int t = 1; t < 7; ++t) j += (i >= jobs.pref[t]);
    const int off = i - jobs.pref[j];
    const float4 v = ((const float4*)jobs.src[j])[off];
    ushort4 o;
    o.x = f2bf(v.x); o.y = f2bf(v.y); o.z = f2bf(v.z); o.w = f2bf(v.w);
    ((ushort4*)jobs.dst[j])[off] = o;
  }
}

// ---------------------------------------------------------------------------
// 2. RoPE tables: cos/sin(s * 10000^(-i/32)), i in [0,32)
// ---------------------------------------------------------------------------
__global__ void rope_tables(float* __restrict__ cost, float* __restrict__ sint, int S) {
  const int idx = blockIdx.x * blockDim.x + threadIdx.x;
  if (idx >= S * 32) return;
  const int s = idx >> 5, i = idx & 31;
  const float invf = powf(10000.0f, -(float)i * (1.0f / 32.0f));
  const float ang = (float)s * invf;
  cost[idx] = cosf(ang);
  sint[idx] = sinf(ang);
}

// ---------------------------------------------------------------------------
// 3/5. GEMM  C = A[M,K] @ Bt[N,K]^T + bias, fused epilogues.
//   MODE 0: Q -> RoPE -> *SCALE_Q -> [bh][s][64]
//   MODE 1: K -> RoPE ->            [bh][s][64]
//   MODE 2: V -> transpose ->       [bh][64][s]
//   MODE 3: f32 token-major [M][N]  (output projection)
//   128x128 tile, BK=64, 4 waves, 16x16x32 MFMA, XOR-swizzled LDS via
//   pre-swizzled global source. 1D grid 512, XCD-chunked remap:
//   each XCD owns 8 consecutive m-panels (A ~2.1MB) x all n (B 2MB) -> L2-fit.
//   Hardcoded: M=8192, N=K=1024, S=2048, H=16, dk=64.
// ---------------------------------------------------------------------------
template<int MODE>
__global__ __launch_bounds__(256, 2)
void gemm_fused(const u16* __restrict__ A, const u16* __restrict__ Bt,
                const float* __restrict__ bias, void* __restrict__ Cout,
                const float* __restrict__ cost, const float* __restrict__ sint,
                int M, int N, int K, int S) {
  __shared__ u16 As[128 * 64];
  __shared__ u16 Bs[128 * 64];
  const int tid = threadIdx.x;
  const int wid = tid >> 6;
  const int lane = tid & 63;
  const int g = lane >> 4, c = lane & 15;

  // XCD-chunked remap (hw round-robins linear id over 8 XCDs)
  const int xcd = blockIdx.x & 7;
  const int slot = blockIdx.x >> 3;
  const int mPerX = (M >> 7) >> 3;               // 8
  const int m0 = (xcd * mPerX + (slot % mPerX)) << 7;
  const int n0 = (slot / mPerX) << 7;

  const int wr = wid >> 1, wc = wid & 1;

  f32x4 acc[4][4];
#pragma unroll
  for (int i = 0; i < 4; ++i)
#pragma unroll
    for (int j = 0; j < 4; ++j) acc[i][j] = (f32x4)(0.0f);

  const int kIters = K >> 6;
  for (int kt = 0; kt < kIters; ++kt) {
    const int k0 = kt << 6;
#pragma unroll
    for (int i = 0; i < 4; ++i) {
      const int chunk = i * 256 + tid;
      const int row = chunk >> 3;
      const int scz = (chunk & 7) ^ (row & 7);
      gload_lds16(A + (size_t)(m0 + row) * K + (k0 + scz * 8),
                  (char*)As + (size_t)(i * 256 + (wid << 6)) * 16);
      gload_lds16(Bt + (size_t)(n0 + row) * K + (k0 + scz * 8),
                  (char*)Bs + (size_t)(i * 256 + (wid << 6)) * 16);
    }
    __syncthreads();
#pragma unroll
    for (int ks = 0; ks < 2; ++ks) {
      short8 af[4], bfr[4];
#pragma unroll
      for (int mi = 0; mi < 4; ++mi) {
        const int row = wr * 64 + mi * 16 + c;
        const int cch = (g + ks * 4) ^ (row & 7);
        af[mi] = *(const short8*)((const char*)As + row * 128 + cch * 16);
      }
#pragma unroll
      for (int ni = 0; ni < 4; ++ni) {
        const int row = wc * 64 + ni * 16 + c;
        const int cch = (g + ks * 4) ^ (row & 7);
        bfr[ni] = *(const short8*)((const char*)Bs + row * 128 + cch * 16);
      }
#pragma unroll
      for (int mi = 0; mi < 4; ++mi)
#pragma unroll
        for (int ni = 0; ni < 4; ++ni)
          acc[mi][ni] = __builtin_amdgcn_mfma_f32_16x16x32_bf16(af[mi], bfr[ni], acc[mi][ni], 0, 0, 0);
    }
    __syncthreads();
  }

  float bv[4];
#pragma unroll
  for (int ni = 0; ni < 4; ++ni) bv[ni] = bias[n0 + wc * 64 + ni * 16 + c];

  // C/D layout: col = lane&15, row = (lane>>4)*4 + reg  [m89/m91 verified]
  if (MODE == 3) {
#pragma unroll
    for (int mi = 0; mi < 4; ++mi)
#pragma unroll
      for (int ni = 0; ni < 4; ++ni)
#pragma unroll
        for (int r = 0; r < 4; ++r) {
          const int row = m0 + wr * 64 + mi * 16 + g * 4 + r;
          const int col = n0 + wc * 64 + ni * 16 + c;
          ((float*)Cout)[(size_t)row * N + col] = acc[mi][ni][r] + bv[ni];
        }
  } else if (MODE == 2) {
    // V: +bias, transpose to [bh][64][S]; 4 consecutive tokens -> ushort4
#pragma unroll
    for (int mi = 0; mi < 4; ++mi) {
      const int row_base = m0 + wr * 64 + mi * 16 + g * 4;
      const int s = row_base & 2047;            // S = 2048
      const int b = row_base >> 11;
#pragma unroll
      for (int ni = 0; ni < 4; ++ni) {
        const int col = n0 + wc * 64 + ni * 16 + c;
        const int h = col >> 6;
        const int d = ni * 16 + c;              // col & 63
        ushort4 w;
        w.x = f2bf(acc[mi][ni][0] + bv[ni]);
        w.y = f2bf(acc[mi][ni][1] + bv[ni]);
        w.z = f2bf(acc[mi][ni][2] + bv[ni]);
        w.w = f2bf(acc[mi][ni][3] + bv[ni]);
        *(ushort4*)((u16*)Cout + ((size_t)(b * 16 + h) * 64 + d) * (size_t)S + s) = w;
      }
    }
  } else {
    // Q/K: +bias, RoPE on pairs (ni, ni+2) == (d, d+32), Q also *SCALE_Q
#pragma unroll
    for (int mi = 0; mi < 4; ++mi)
#pragma unroll
      for (int pair = 0; pair < 2; ++pair) {
        const int d_lo = pair * 16 + c;         // in [0,32) -> freq index i
        const int col_lo = n0 + wc * 64 + d_lo;
        const int h = col_lo >> 6;
#pragma unroll
        for (int r = 0; r < 4; ++r) {
          const int row = m0 + wr * 64 + mi * 16 + g * 4 + r;
          const int s = row & 2047;             // S = 2048
          const int b = row >> 11;
          const float co = cost[s * 32 + d_lo];
          const float si = sint[s * 32 + d_lo];
          const float vlo = acc[mi][pair][r] + bv[pair];
          const float vhi = acc[mi][pair + 2][r] + bv[pair + 2];
          float olo = vlo * co - vhi * si;
          float ohi = vhi * co + vlo * si;
          if (MODE == 0) { olo *= SCALE_Q; ohi *= SCALE_Q; }
          u16* dst = (u16*)Cout + ((size_t)(b * 16 + h) * S + s) * 64 + d_lo;
          dst[0]  = f2bf(olo);
          dst[32] = f2bf(ohi);
        }
      }
  }
}

// ---------------------------------------------------------------------------
// 4. causal flash attention (unchanged from round 4).
//   Swapped-operand MFMA: Sc^T = K x Q^T, O^T = V^T x P^T. 4 waves x 32 q.
//   Fold-pairing -> uniform 36 k-tiles/block. 2-phase double-buffered staging.
//   XCD-clustered remap. Q pre-scaled (exp2 domain); defer-max THR=8.
// ---------------------------------------------------------------------------
__global__ __launch_bounds__(256, 3)
void attn_kernel(const u16* __restrict__ Qh, const u16* __restrict__ Kh,
                 const u16* __restrict__ Vt, u16* __restrict__ ctx,
                 int B, int H, int S) {
  __shared__ u16 KV[2][2][64 * 64];   // [buf][K=0/V=1], 32 KiB
  __shared__ u16 Ps[4][16 * 64];      // per-wave P tile (reused per qf), 8 KiB
  const int tid = threadIdx.x, wid = tid >> 6, lane = tid & 63;
  const int g = lane >> 4, c = lane & 15;

  const int nstH = gridDim.x;              // NST/2
  const int nwg = nstH * gridDim.y;
  const int lin = blockIdx.x + nstH * blockIdx.y;
  const int tt = (lin & 7) * (nwg >> 3) + (lin >> 3);
  const int bx = tt % nstH;
  const int bh = tt / nstH;
  const int b = bh / H, h = bh % H;
  const int D = H * 64;
  const int NST = nstH * 2;

  const size_t baseQK = (size_t)bh * S * 64;
  const size_t baseV  = (size_t)bh * 64 * S;

  for (int ph = 0; ph < 2; ++ph) {
    const int stile = ph ? (NST - 1 - bx) : bx;
    const int q0 = stile * 128;
    const int KT = (q0 >> 6) + 2;
    const int q0w = q0 + wid * 32;
    const int ktl = (q0w + 31) >> 6;
    const int qg0 = q0w + c, qg1 = q0w + 16 + c;

    short8 qB[2][2];
#pragma unroll
    for (int qf = 0; qf < 2; ++qf)
#pragma unroll
      for (int ks = 0; ks < 2; ++ks)
        qB[qf][ks] = *(const short8*)(Qh + baseQK +
                       (size_t)(q0w + qf * 16 + c) * 64 + ks * 32 + g * 8);

    float m_r[2], l_r[2];
    m_r[0] = m_r[1] = -__builtin_inff();
    l_r[0] = l_r[1] = 0.0f;
    f32x4 o[4][2];
#pragma unroll
    for (int df = 0; df < 4; ++df) { o[df][0] = (f32x4)(0.0f); o[df][1] = (f32x4)(0.0f); }

    auto stage = [&](int buf, int kt) {
#pragma unroll
      for (int i = 0; i < 2; ++i) {
        const int chunk = i * 256 + tid;
        const int row = chunk >> 3;
        const int scz = (chunk & 7) ^ (row & 7);
        gload_lds16(Kh + baseQK + (size_t)(kt * 64 + row) * 64 + scz * 8,
                    (char*)&KV[buf][0][0] + (size_t)(i * 256 + (wid << 6)) * 16);
        gload_lds16(Vt + baseV + (size_t)row * S + (kt * 64 + scz * 8),
                    (char*)&KV[buf][1][0] + (size_t)(i * 256 + (wid << 6)) * 16);
      }
    };

    stage(0, 0);
    __syncthreads();
    int cur = 0;
    for (int kt = 0; kt < KT; ++kt) {
      if (kt + 1 < KT) stage(cur ^ 1, kt + 1);
      if (kt <= ktl) {
        const char* Kb = (const char*)&KV[cur][0][0];
        const char* Vb = (const char*)&KV[cur][1][0];

        f32x4 sc[4][2];
#pragma unroll
        for (int kf = 0; kf < 4; ++kf) { sc[kf][0] = (f32x4)(0.0f); sc[kf][1] = (f32x4)(0.0f); }
#pragma unroll
        for (int ks = 0; ks < 2; ++ks) {
          short8 kA[4];
#pragma unroll
          for (int kf = 0; kf < 4; ++kf) {
            const int row = kf * 16 + c;
            kA[kf] = *(const short8*)(Kb + row * 128 + (((g + 4 * ks) ^ (row & 7))) * 16);
          }
#pragma unroll
          for (int kf = 0; kf < 4; ++kf) {
            sc[kf][0] = __builtin_amdgcn_mfma_f32_16x16x32_bf16(kA[kf], qB[0][ks], sc[kf][0], 0, 0, 0);
            sc[kf][1] = __builtin_amdgcn_mfma_f32_16x16x32_bf16(kA[kf], qB[1][ks], sc[kf][1], 0, 0, 0);
          }
        }

        if (kt == ktl) {
#pragma unroll
          for (int kf = 0; kf < 4; ++kf)
#pragma unroll
            for (int r = 0; r < 4; ++r) {
              const int kg = kt * 64 + kf * 16 + 4 * g + r;
              if (kg > qg0) sc[kf][0][r] = -__builtin_inff();
              if (kg > qg1) sc[kf][1][r] = -__builtin_inff();
            }
        }

        u16* Pw = &Ps[wid][0];
        short8 pB[2][2];
#pragma unroll
        for (int qf = 0; qf < 2; ++qf) {
          f32x4 mm = max4(max4(sc[0][qf], sc[1][qf]), max4(sc[2][qf], sc[3][qf]));
          float pm = fmaxf(fmaxf(mm[0], mm[1]), fmaxf(mm[2], mm[3]));
          pm = fmaxf(pm, __shfl_xor(pm, 16));
          pm = fmaxf(pm, __shfl_xor(pm, 32));
          if (__any(pm > m_r[qf] + 8.0f)) {
            const float mn = fmaxf(m_r[qf], pm);
            const float rs = __builtin_exp2f(m_r[qf] - mn);
            m_r[qf] = mn; l_r[qf] *= rs;
#pragma unroll
            for (int df = 0; df < 4; ++df) o[df][qf] *= rs;
          }
          f32x4 ps4 = (f32x4)(0.0f);
#pragma unroll
          for (int kf = 0; kf < 4; ++kf) {
            f32x4 pv;
#pragma unroll
            for (int r = 0; r < 4; ++r) pv[r] = __builtin_exp2f(sc[kf][qf][r] - m_r[qf]);
            sc[kf][qf] = pv;
            ps4 += pv;
          }
          float psum = (ps4[0] + ps4[1]) + (ps4[2] + ps4[3]);
          psum += __shfl_xor(psum, 16);
          psum += __shfl_xor(psum, 32);
          l_r[qf] += psum;

#pragma unroll
          for (int kf = 0; kf < 4; ++kf) {
            ushort4 pk;
            pk.x = f2bf(sc[kf][qf][0]); pk.y = f2bf(sc[kf][qf][1]);
            pk.z = f2bf(sc[kf][qf][2]); pk.w = f2bf(sc[kf][qf][3]);
            *(ushort4*)((char*)Pw + c * 128 +
                        (((2 * kf + (g >> 1)) ^ (c & 7))) * 16 + 8 * (g & 1)) = pk;
          }
#pragma unroll
          for (int ks = 0; ks < 2; ++ks)
            pB[qf][ks] = *(const short8*)((const char*)Pw + c * 128 +
                                          (((g + 4 * ks) ^ (c & 7))) * 16);
        }

#pragma unroll
        for (int ks = 0; ks < 2; ++ks)
#pragma unroll
          for (int df = 0; df < 4; ++df) {
            const int row = df * 16 + c;
            const short8 va = *(const short8*)(Vb + row * 128 + (((g + 4 * ks) ^ (row & 7))) * 16);
            o[df][0] = __builtin_amdgcn_mfma_f32_16x16x32_bf16(va, pB[0][ks], o[df][0], 0, 0, 0);
            o[df][1] = __builtin_amdgcn_mfma_f32_16x16x32_bf16(va, pB[1][ks], o[df][1], 0, 0, 0);
          }
      }
      __syncthreads();
      cur ^= 1;
    }

#pragma unroll
    for (int qf = 0; qf < 2; ++qf) {
      const float inv = 1.0f / l_r[qf];
      u16* rowp = ctx + (size_t)(b * S + q0w + qf * 16 + c) * D + h * 64;
#pragma unroll
      for (int df = 0; df < 4; ++df) {
        ushort4 w;
        w.x = f2bf(o[df][qf][0] * inv); w.y = f2bf(o[df][qf][1] * inv);
        w.z = f2bf(o[df][qf][2] * inv); w.w = f2bf(o[df][qf][3] * inv);
        *(ushort4*)(rowp + df * 16 + 4 * g) = w;
      }
    }
  }
}

// ---------------------------------------------------------------------------
extern "C" void kernel_launch(void* const* d_in, const int* in_sizes, int n_in,
                              void* d_out, int out_size, void* d_ws, size_t ws_size,
                              hipStream_t stream) {
  const float* query = (const float*)d_in[0];
  const float* key   = (const float*)d_in[1];
  const float* value = (const float*)d_in[2];
  const float* W_q = (const float*)d_in[3];
  const float* b_q = (const float*)d_in[4];
  const float* W_k = (const float*)d_in[5];
  const float* b_k = (const float*)d_in[6];
  const float* W_v = (const float*)d_in[7];
  const float* b_v = (const float*)d_in[8];
  const float* W_o = (const float*)d_in[9];
  const float* b_o = (const float*)d_in[10];

  const int D = 1024, H = 16, S = 2048;
  const int BS = in_sizes[0] / D;          // B * S = 8192
  const int B = BS / S;

  const size_t nX = (size_t)BS * D;        // 8.4M elems
  const size_t nW = (size_t)D * D;
  u16* p = (u16*)d_ws;
  u16* xq = p;  p += nX;
  u16* xk = p;  p += nX;
  u16* xv = p;  p += nX;
  u16* wq = p;  p += nW;
  u16* wk = p;  p += nW;
  u16* wv = p;  p += nW;
  u16* wo = p;  p += nW;
  u16* Qh = p;  p += nX;
  u16* Kh = p;  p += nX;
  u16* Vtr = p; p += nX;
  float* cost = (float*)p;
  float* sint = cost + (size_t)S * 32;
  u16* ctx = xq;   // alias: xq dead after Q-projection GEMM

  // one-shot cvt of all 7 fp32 buffers
  CvtJobs jobs;
  jobs.src[0] = query; jobs.src[1] = key; jobs.src[2] = value;
  jobs.src[3] = W_q;   jobs.src[4] = W_k; jobs.src[5] = W_v; jobs.src[6] = W_o;
  jobs.dst[0] = xq; jobs.dst[1] = xk; jobs.dst[2] = xv;
  jobs.dst[3] = wq; jobs.dst[4] = wk; jobs.dst[5] = wv; jobs.dst[6] = wo;
  const int a4 = (int)(nX / 4), w4 = (int)(nW / 4);
  jobs.pref[0] = 0;
  jobs.pref[1] = a4;     jobs.pref[2] = 2 * a4; jobs.pref[3] = 3 * a4;
  jobs.pref[4] = 3 * a4 + w4;     jobs.pref[5] = 3 * a4 + 2 * w4;
  jobs.pref[6] = 3 * a4 + 3 * w4; jobs.pref[7] = 3 * a4 + 4 * w4;
  cvt_all<<<2048, 256, 0, stream>>>(jobs, jobs.pref[7]);

  rope_tables<<<(S * 32 + 255) / 256, 256, 0, stream>>>(cost, sint, S);

  const int gblocks = (BS / 128) * (D / 128);   // 512
  gemm_fused<0><<<gblocks, 256, 0, stream>>>(xq, wq, b_q, Qh,  cost, sint, BS, D, D, S);
  gemm_fused<1><<<gblocks, 256, 0, stream>>>(xk, wk, b_k, Kh,  cost, sint, BS, D, D, S);
  gemm_fused<2><<<gblocks, 256, 0, stream>>>(xv, wv, b_v, Vtr, cost, sint, BS, D, D, S);

  attn_kernel<<<dim3(S / 256, B * H), 256, 0, stream>>>(Qh, Kh, Vtr, ctx, B, H, S);

  gemm_fused<3><<<gblocks, 256, 0, stream>>>(ctx, wo, b_o, d_out, cost, sint, BS, D, D, S);
}